// Round 5
// baseline (805.655 us; speedup 1.0000x reference)
//
#include <hip/hip_runtime.h>

#define HS   512
#define WSZ  512
#define NC   64
#define HW   (HS * WSZ)
#define KCAP 16

typedef unsigned int uint;
typedef unsigned short ushort;

// float -> bf16 (round-to-nearest-even), raw bits
__device__ __forceinline__ ushort f2bf(float f) {
    uint b = __float_as_uint(f);
    return (ushort)((b + 0x7FFFu + ((b >> 16) & 1u)) >> 16);
}

// ---------------------------------------------------------------------------
// prep: transpose ref (C,H,W) f32 -> refu4 (H*W, 8) uint4 (packed bf16 pairs,
// 64 ch/pixel = 128B), zero bin counters.  float4 reads, uint4 writes.
// ---------------------------------------------------------------------------
__global__ __launch_bounds__(256) void prep_kernel(
    const float4* __restrict__ ref4, uint4* __restrict__ refu4,
    int* __restrict__ cnt)
{
    __shared__ float lds[64 * 65];
    const int p0  = blockIdx.x * 64;       // 64 pixels / tile
    const int tid = threadIdx.x;
    if (tid < 64) cnt[blockIdx.x * 64 + tid] = 0;    // 4096*64 == HW
#pragma unroll
    for (int k = 0; k < 4; ++k) {
        int e  = k * 256 + tid;            // 1024 float4 per tile
        int c  = e >> 4;                   // channel
        int i4 = e & 15;                   // pixel quad
        float4 v = ref4[(size_t)c * (HW / 4) + (p0 >> 2) + i4];
        lds[(i4 * 4 + 0) * 65 + c] = v.x;
        lds[(i4 * 4 + 1) * 65 + c] = v.y;
        lds[(i4 * 4 + 2) * 65 + c] = v.z;
        lds[(i4 * 4 + 3) * 65 + c] = v.w;
    }
    __syncthreads();
#pragma unroll
    for (int k = 0; k < 2; ++k) {
        int e = k * 256 + tid;             // 512 uint4 per tile
        int i = e >> 3;                    // pixel
        int q = e & 7;                     // channel octet
        const float* row = &lds[i * 65 + 8 * q];
        uint4 u;
        u.x = (uint)f2bf(row[0]) | ((uint)f2bf(row[1]) << 16);
        u.y = (uint)f2bf(row[2]) | ((uint)f2bf(row[3]) << 16);
        u.z = (uint)f2bf(row[4]) | ((uint)f2bf(row[5]) << 16);
        u.w = (uint)f2bf(row[6]) | ((uint)f2bf(row[7]) << 16);
        refu4[(size_t)(p0 + i) * 8 + q] = u;
    }
}

// ---------------------------------------------------------------------------
// Invert nnf_rs into fixed-capacity bins (bin = nnf_rs value = scatter
// target center).  Poisson(1)/bin; P(count>16) ~ 1e-14.
// ---------------------------------------------------------------------------
__global__ __launch_bounds__(256) void fill_bins(
    const int2* __restrict__ nnf_rs, int* __restrict__ cnt,
    int* __restrict__ slots)
{
    int r = blockIdx.x * 256 + threadIdx.x;
    int2 s = nnf_rs[r];                 // (sy, sx), values in [0,512)
    int bin = (s.x << 9) | s.y;
    int pos = atomicAdd(&cnt[bin], 1);
    if (pos < KCAP) slots[(bin << 4) + pos] = r;
}

// ---------------------------------------------------------------------------
// Gather: 8 targets/wave, 8 lanes/target, lane covers 8 channels via one
// uint4 (16B).  Pass-2 walks a register-compacted entry list; per-tap state
// in EXPLICIT SCALARS (no alloca -> no LDS).
// __launch_bounds__(256,4): 128-VGPR budget — R4's (256,6) forced an 85-VGPR
// cap and spilled the hot-loop state to scratch (2.8 GB of spill traffic).
// ---------------------------------------------------------------------------
template <bool PACKED>
__global__ __launch_bounds__(256, 4) void gather8(
    const uint4* __restrict__ refu4,
    const float* __restrict__ reff,
    const int2*  __restrict__ nnf_sr,
    const int*   __restrict__ cnt,
    const int*   __restrict__ slots,
    float* __restrict__ out)
{
    const float ws = 1.0f / 262144.0f;   // 2^-18 exact
    const float wr = 2.0f / 262144.0f;   // 2^-17 exact

    const int tid = threadIdx.x;
    const int k   = tid & 7;                       // channel octet
    const int t   = blockIdx.x * 32 + (tid >> 3);  // 32 targets / block
    const int ty  = t >> 9, tx = t & 511;

    float a0=0,a1=0,a2=0,a3=0,a4=0,a5=0,a6=0,a7=0, w=0.f;

    auto accum = [&](int q, float m) {
        if (PACKED) {
            uint4 u = refu4[(size_t)q * 8 + k];
            a0 += __uint_as_float(u.x << 16)         * m;
            a1 += __uint_as_float(u.x & 0xffff0000u) * m;
            a2 += __uint_as_float(u.y << 16)         * m;
            a3 += __uint_as_float(u.y & 0xffff0000u) * m;
            a4 += __uint_as_float(u.z << 16)         * m;
            a5 += __uint_as_float(u.z & 0xffff0000u) * m;
            a6 += __uint_as_float(u.w << 16)         * m;
            a7 += __uint_as_float(u.w & 0xffff0000u) * m;
        } else {
            const size_t c0 = (size_t)(8 * k) * HW + q;
            a0 += reff[c0 + 0*(size_t)HW] * m;  a1 += reff[c0 + 1*(size_t)HW] * m;
            a2 += reff[c0 + 2*(size_t)HW] * m;  a3 += reff[c0 + 3*(size_t)HW] * m;
            a4 += reff[c0 + 4*(size_t)HW] * m;  a5 += reff[c0 + 5*(size_t)HW] * m;
            a6 += reff[c0 + 6*(size_t)HW] * m;  a7 += reff[c0 + 7*(size_t)HW] * m;
        }
        w += m;
    };

    // Explicit scalars: cbN = (slots base)|tap-id, pfN = prefix offset.
    int cb0,cb1,cb2,cb3,cb4,cb5,cb6,cb7,cb8;
    int pf0,pf1,pf2,pf3,pf4,pf5,pf6,pf7,pf8;
    int run = 0;

#define TAP(i, dy, dx)                                                        \
    {                                                                         \
        const int sy = ty - (dy), sx = tx - (dx);                             \
        const bool sval = ((unsigned)sy < 512u) & ((unsigned)sx < 512u);      \
        const int sidx = ((sy & 511) << 9) | (sx & 511);                      \
        cb##i = (sidx << 4) | i;                                              \
        pf##i = run;                                                          \
        const int c = cnt[sidx];                                              \
        run += sval ? min(c, KCAP) : 0;                                       \
        const int2 nn = nnf_sr[sidx];                                         \
        const int qy = nn.x + (dy), qx = nn.y + (dx);                         \
        const bool v = sval & ((unsigned)qy < 512u) & ((unsigned)qx < 512u);  \
        const int q  = ((qy & 511) << 9) | (qx & 511);                        \
        accum(q, v ? ws : 0.f);                                               \
    }

    // ---- pass 1 (src->ref gather) + per-tap metadata / prefix sums ----
    TAP(0, -1, -1)  TAP(1, -1, 0)  TAP(2, -1, 1)
    TAP(3,  0, -1)  TAP(4,  0, 0)  TAP(5,  0, 1)
    TAP(6,  1, -1)  TAP(7,  1, 0)  TAP(8,  1, 1)
#undef TAP

    const int S = run;

    // ---- pass 2: compacted entry walk, branch-free register select ----
#define SEL(i)                                                                \
    {                                                                         \
        const bool cnd = (s >= pf##i);                                        \
        w1  = cnd ? cb##i : w1;                                               \
        off = cnd ? pf##i : off;                                              \
    }
    auto entry = [&](int s) {
        int w1 = cb0, off = pf0;
        SEL(1) SEL(2) SEL(3) SEL(4) SEL(5) SEL(6) SEL(7) SEL(8)
        const int ii  = w1 & 15;                    // tap id
        const int idx = min(s - off, KCAP - 1);     // clamp: addr stays valid
        const int e   = slots[(w1 & ~15) + idx];
        const int ry  = (e >> 9) & 511, rx = e & 511;
        const int dyp = (ii * 11) >> 5;             // ii/3
        const int dy  = dyp - 1, dx = ii - 3 * dyp - 1;
        const int qy  = ry + dy, qx = rx + dx;
        const bool v  = (s < S) & ((unsigned)qy < 512u) & ((unsigned)qx < 512u);
        const int q   = ((qy & 511) << 9) | (qx & 511);
        accum(q, v ? wr : 0.f);
    };
#undef SEL

    for (int s = 0; s < S; s += 2) {   // x2 for MLP
        entry(s);
        entry(s + 1);
    }

    // ---- epilogue ----
    if (w == 0.f) w = 1.f;
    const float inv = 1.f / w;
    size_t o = (size_t)(8 * k) * HW + t;
    out[o]                = a0 * inv;
    out[o + 1*(size_t)HW] = a1 * inv;
    out[o + 2*(size_t)HW] = a2 * inv;
    out[o + 3*(size_t)HW] = a3 * inv;
    out[o + 4*(size_t)HW] = a4 * inv;
    out[o + 5*(size_t)HW] = a5 * inv;
    out[o + 6*(size_t)HW] = a6 * inv;
    out[o + 7*(size_t)HW] = a7 * inv;
}

extern "C" void kernel_launch(void* const* d_in, const int* in_sizes, int n_in,
                              void* d_out, int out_size, void* d_ws, size_t ws_size,
                              hipStream_t stream)
{
    const float* ref    = (const float*)d_in[0];
    const int2*  nnf_sr = (const int2*)d_in[1];
    const int2*  nnf_rs = (const int2*)d_in[2];
    float* out = (float*)d_out;

    char* wsb = (char*)d_ws;
    const size_t refT_bytes = (size_t)HW * NC * 2;        // 32 MiB packed bf16
    const size_t cnt_bytes  = (size_t)HW * 4;             //  1 MiB
    const size_t slot_bytes = (size_t)HW * KCAP * 4;      // 16 MiB

    if (ws_size >= refT_bytes + cnt_bytes + slot_bytes) {
        uint4* refu4 = (uint4*)wsb;
        int*   cntp  = (int*)(wsb + refT_bytes);
        int*   slots = (int*)(wsb + refT_bytes + cnt_bytes);

        prep_kernel<<<HW / 64, 256, 0, stream>>>((const float4*)ref, refu4, cntp);
        fill_bins<<<HW / 256, 256, 0, stream>>>(nnf_rs, cntp, slots);
        gather8<true><<<HW / 32, 256, 0, stream>>>(refu4, nullptr, nnf_sr,
                                                   cntp, slots, out);
    } else {
        // fallback: bins only, gather channel-major f32 ref directly
        int* cntp  = (int*)wsb;
        int* slots = cntp + HW;
        hipMemsetAsync(cntp, 0, cnt_bytes, stream);
        fill_bins<<<HW / 256, 256, 0, stream>>>(nnf_rs, cntp, slots);
        gather8<false><<<HW / 32, 256, 0, stream>>>(nullptr, ref, nnf_sr,
                                                    cntp, slots, out);
    }
}

// Round 6
// 234.801 us; speedup vs baseline: 3.4312x; 3.4312x over previous
//
#include <hip/hip_runtime.h>

#define HS   512
#define WSZ  512
#define NC   64
#define HW   (HS * WSZ)
#define KCAP 16

typedef unsigned int uint;
typedef unsigned short ushort;

// float -> bf16 (round-to-nearest-even), raw bits
__device__ __forceinline__ ushort f2bf(float f) {
    uint b = __float_as_uint(f);
    return (ushort)((b + 0x7FFFu + ((b >> 16) & 1u)) >> 16);
}

// ---------------------------------------------------------------------------
// prep: transpose ref (C,H,W) f32 -> refu4 (H*W, 8) uint4 (packed bf16 pairs,
// 64 ch/pixel = 128B), zero bin counters.  float4 reads, uint4 writes.
// ---------------------------------------------------------------------------
__global__ __launch_bounds__(256) void prep_kernel(
    const float4* __restrict__ ref4, uint4* __restrict__ refu4,
    int* __restrict__ cnt)
{
    __shared__ float lds[64 * 65];
    const int p0  = blockIdx.x * 64;       // 64 pixels / tile
    const int tid = threadIdx.x;
    if (tid < 64) cnt[blockIdx.x * 64 + tid] = 0;    // 4096*64 == HW
#pragma unroll
    for (int k = 0; k < 4; ++k) {
        int e  = k * 256 + tid;            // 1024 float4 per tile
        int c  = e >> 4;                   // channel
        int i4 = e & 15;                   // pixel quad
        float4 v = ref4[(size_t)c * (HW / 4) + (p0 >> 2) + i4];
        lds[(i4 * 4 + 0) * 65 + c] = v.x;
        lds[(i4 * 4 + 1) * 65 + c] = v.y;
        lds[(i4 * 4 + 2) * 65 + c] = v.z;
        lds[(i4 * 4 + 3) * 65 + c] = v.w;
    }
    __syncthreads();
#pragma unroll
    for (int k = 0; k < 2; ++k) {
        int e = k * 256 + tid;             // 512 uint4 per tile
        int i = e >> 3;                    // pixel
        int q = e & 7;                     // channel octet
        const float* row = &lds[i * 65 + 8 * q];
        uint4 u;
        u.x = (uint)f2bf(row[0]) | ((uint)f2bf(row[1]) << 16);
        u.y = (uint)f2bf(row[2]) | ((uint)f2bf(row[3]) << 16);
        u.z = (uint)f2bf(row[4]) | ((uint)f2bf(row[5]) << 16);
        u.w = (uint)f2bf(row[6]) | ((uint)f2bf(row[7]) << 16);
        refu4[(size_t)(p0 + i) * 8 + q] = u;
    }
}

// ---------------------------------------------------------------------------
// Invert nnf_rs into fixed-capacity bins (bin = nnf_rs value = scatter
// target center).  Poisson(1)/bin; P(count>16) ~ 1e-14.
// ---------------------------------------------------------------------------
__global__ __launch_bounds__(256) void fill_bins(
    const int2* __restrict__ nnf_rs, int* __restrict__ cnt,
    int* __restrict__ slots)
{
    int r = blockIdx.x * 256 + threadIdx.x;
    int2 s = nnf_rs[r];                 // (sy, sx), values in [0,512)
    int bin = (s.x << 9) | s.y;
    int pos = atomicAdd(&cnt[bin], 1);
    if (pos < KCAP) slots[(bin << 4) + pos] = r;
}

// ---------------------------------------------------------------------------
// Gather: 8 targets/wave, 8 lanes/target, lane covers 8 channels via one
// uint4 (16B).  NO LAMBDAS — R4/R5's by-reference lambda captures were
// materialized as a scratch frame (VGPR=28, ~2.7GB scratch traffic).  All
// state in named scalars, straight-line macro-expanded code.
// Tap metadata packed in ONE int: (sidx<<12)|(tap<<8)|prefix  (30 bits).
// ---------------------------------------------------------------------------
template <bool PACKED>
__global__ __launch_bounds__(256) void gather8(
    const uint4* __restrict__ refu4,
    const float* __restrict__ reff,
    const int2*  __restrict__ nnf_sr,
    const int*   __restrict__ cnt,
    const int*   __restrict__ slots,
    float* __restrict__ out)
{
    const float ws = 1.0f / 262144.0f;   // 2^-18 exact
    const float wr = 2.0f / 262144.0f;   // 2^-17 exact

    const int tid = threadIdx.x;
    const int k   = tid & 7;                       // channel octet
    const int t   = blockIdx.x * 32 + (tid >> 3);  // 32 targets / block
    const int ty  = t >> 9, tx = t & 511;

    float a0=0,a1=0,a2=0,a3=0,a4=0,a5=0,a6=0,a7=0, w=0.f;

#define ACCUM(qv, mv)                                                         \
    {                                                                         \
        const int   q_ = (qv);                                                \
        const float m_ = (mv);                                                \
        if (PACKED) {                                                         \
            uint4 u_ = refu4[(size_t)q_ * 8 + k];                             \
            a0 += __uint_as_float(u_.x << 16)         * m_;                   \
            a1 += __uint_as_float(u_.x & 0xffff0000u) * m_;                   \
            a2 += __uint_as_float(u_.y << 16)         * m_;                   \
            a3 += __uint_as_float(u_.y & 0xffff0000u) * m_;                   \
            a4 += __uint_as_float(u_.z << 16)         * m_;                   \
            a5 += __uint_as_float(u_.z & 0xffff0000u) * m_;                   \
            a6 += __uint_as_float(u_.w << 16)         * m_;                   \
            a7 += __uint_as_float(u_.w & 0xffff0000u) * m_;                   \
        } else {                                                              \
            const size_t c0_ = (size_t)(8 * k) * HW + q_;                     \
            a0 += reff[c0_ + 0*(size_t)HW] * m_;                              \
            a1 += reff[c0_ + 1*(size_t)HW] * m_;                              \
            a2 += reff[c0_ + 2*(size_t)HW] * m_;                              \
            a3 += reff[c0_ + 3*(size_t)HW] * m_;                              \
            a4 += reff[c0_ + 4*(size_t)HW] * m_;                              \
            a5 += reff[c0_ + 5*(size_t)HW] * m_;                              \
            a6 += reff[c0_ + 6*(size_t)HW] * m_;                              \
            a7 += reff[c0_ + 7*(size_t)HW] * m_;                              \
        }                                                                     \
        w += m_;                                                              \
    }

    // mtN = (sidx<<12) | (tap<<8) | prefix   (prefix <= 144 fits in 8 bits)
    int mt0,mt1,mt2,mt3,mt4,mt5,mt6,mt7,mt8;
    int run = 0;

#define TAP(i, dy, dx)                                                        \
    {                                                                         \
        const int sy = ty - (dy), sx = tx - (dx);                             \
        const bool sval = ((unsigned)sy < 512u) & ((unsigned)sx < 512u);      \
        const int sidx = ((sy & 511) << 9) | (sx & 511);                      \
        mt##i = (sidx << 12) | ((i) << 8) | run;                              \
        const int c = cnt[sidx];                                              \
        run += sval ? min(c, KCAP) : 0;                                       \
        const int2 nn = nnf_sr[sidx];                                         \
        const int qy = nn.x + (dy), qx = nn.y + (dx);                         \
        const bool v = sval & ((unsigned)qy < 512u) & ((unsigned)qx < 512u);  \
        ACCUM((((qy & 511) << 9) | (qx & 511)), v ? ws : 0.f)                 \
    }

    // ---- pass 1 (src->ref gather) + per-tap metadata / prefix sums ----
    TAP(0, -1, -1)  TAP(1, -1, 0)  TAP(2, -1, 1)
    TAP(3,  0, -1)  TAP(4,  0, 0)  TAP(5,  0, 1)
    TAP(6,  1, -1)  TAP(7,  1, 0)  TAP(8,  1, 1)
#undef TAP

    const int S = run;

    // ---- pass 2: compacted entry walk, branch-free register select ----
#define SEL(i)  m_ = (s_ >= (mt##i & 255)) ? mt##i : m_;
#define ENTRY(sv)                                                             \
    {                                                                         \
        const int s_ = (sv);                                                  \
        int m_ = mt0;                                                         \
        SEL(1) SEL(2) SEL(3) SEL(4) SEL(5) SEL(6) SEL(7) SEL(8)               \
        const int off_ = m_ & 255;                                            \
        const int ii_  = (m_ >> 8) & 15;                                      \
        const int bs_  = (m_ >> 12) << 4;      /* slots base = sidx*16 */     \
        const int idx_ = min(s_ - off_, KCAP - 1);                            \
        const int e_   = slots[bs_ + idx_];                                   \
        const int ry_  = (e_ >> 9) & 511, rx_ = e_ & 511;                     \
        const int dyp_ = (ii_ * 11) >> 5;      /* ii/3 */                     \
        const int dy_  = dyp_ - 1, dx_ = ii_ - 3 * dyp_ - 1;                  \
        const int qy_  = ry_ + dy_, qx_ = rx_ + dx_;                          \
        const bool v_  = (s_ < S) &                                           \
                         ((unsigned)qy_ < 512u) & ((unsigned)qx_ < 512u);     \
        ACCUM((((qy_ & 511) << 9) | (qx_ & 511)), v_ ? wr : 0.f)              \
    }

    for (int s = 0; s < S; s += 2) {   // x2 for MLP
        ENTRY(s)
        ENTRY(s + 1)
    }
#undef ENTRY
#undef SEL
#undef ACCUM

    // ---- epilogue ----
    if (w == 0.f) w = 1.f;             // unreachable (center tap always valid)
    const float inv = 1.f / w;
    size_t o = (size_t)(8 * k) * HW + t;
    out[o]                = a0 * inv;
    out[o + 1*(size_t)HW] = a1 * inv;
    out[o + 2*(size_t)HW] = a2 * inv;
    out[o + 3*(size_t)HW] = a3 * inv;
    out[o + 4*(size_t)HW] = a4 * inv;
    out[o + 5*(size_t)HW] = a5 * inv;
    out[o + 6*(size_t)HW] = a6 * inv;
    out[o + 7*(size_t)HW] = a7 * inv;
}

extern "C" void kernel_launch(void* const* d_in, const int* in_sizes, int n_in,
                              void* d_out, int out_size, void* d_ws, size_t ws_size,
                              hipStream_t stream)
{
    const float* ref    = (const float*)d_in[0];
    const int2*  nnf_sr = (const int2*)d_in[1];
    const int2*  nnf_rs = (const int2*)d_in[2];
    float* out = (float*)d_out;

    char* wsb = (char*)d_ws;
    const size_t refT_bytes = (size_t)HW * NC * 2;        // 32 MiB packed bf16
    const size_t cnt_bytes  = (size_t)HW * 4;             //  1 MiB
    const size_t slot_bytes = (size_t)HW * KCAP * 4;      // 16 MiB

    if (ws_size >= refT_bytes + cnt_bytes + slot_bytes) {
        uint4* refu4 = (uint4*)wsb;
        int*   cntp  = (int*)(wsb + refT_bytes);
        int*   slots = (int*)(wsb + refT_bytes + cnt_bytes);

        prep_kernel<<<HW / 64, 256, 0, stream>>>((const float4*)ref, refu4, cntp);
        fill_bins<<<HW / 256, 256, 0, stream>>>(nnf_rs, cntp, slots);
        gather8<true><<<HW / 32, 256, 0, stream>>>(refu4, nullptr, nnf_sr,
                                                   cntp, slots, out);
    } else {
        // fallback: bins only, gather channel-major f32 ref directly
        int* cntp  = (int*)wsb;
        int* slots = cntp + HW;
        hipMemsetAsync(cntp, 0, cnt_bytes, stream);
        fill_bins<<<HW / 256, 256, 0, stream>>>(nnf_rs, cntp, slots);
        gather8<false><<<HW / 32, 256, 0, stream>>>(nullptr, ref, nnf_sr,
                                                    cntp, slots, out);
    }
}